// Round 7
// baseline (494.633 us; speedup 1.0000x reference)
//
#include <hip/hip_runtime.h>
#include <cmath>

// Problem constants (fixed by the reference).
constexpr int B  = 4096;
constexpr int D  = 768;
constexpr int P  = 96;
constexpr int C  = 256;
constexpr int SD = 8;    // D / P

constexpr int TPB  = 256;   // 4 waves per block
constexpr int WPB  = 4;     // waves per block (centroid split)
constexpr int CPW  = C / WPB;  // 64 centroids per wave
constexpr int ROWS = 4;     // rows per thread

typedef float f32x2 __attribute__((ext_vector_type(2)));

// Packed fp32 FMA: d = {fma(a,b.x,c.x), fma(a,b.y,c.y)} -> v_pk_fma_f32 on
// gfx950 (scalar a broadcast via op_sel). Each half is IEEE fma == fmaf, so
// per-half arithmetic is bit-identical to the validated scalar chain.
__device__ __forceinline__ f32x2 pkfma(float a, f32x2 b, f32x2 c)
{
#if __has_builtin(__builtin_elementwise_fma)
    f32x2 av; av.x = a; av.y = a;
    return __builtin_elementwise_fma(av, b, c);
#else
    f32x2 r; r.x = fmaf(a, b.x, c.x); r.y = fmaf(a, b.y, c.y); return r;
#endif
}

// ---- numpy fp32 emulation helpers (exact path only, validated absmax=0) ----
__device__ __forceinline__ float tree8(float q0, float q1, float q2, float q3,
                                       float q4, float q5, float q6, float q7)
{
#pragma clang fp contract(off)
    return ((q0 + q1) + (q2 + q3)) + ((q4 + q5) + (q6 + q7));
}

__device__ __forceinline__ float proba_np(const float* __restrict__ cbf,
                                          const float* __restrict__ csq,
                                          int c, float4 va, float4 vb, float vsq)
{
#pragma clang fp contract(off)
    float4 ca = ((const float4*)cbf)[2 * c];
    float4 cb = ((const float4*)cbf)[2 * c + 1];
    float p0 = va.x * ca.x, p1 = va.y * ca.y, p2 = va.z * ca.z, p3 = va.w * ca.w;
    float p4 = vb.x * cb.x, p5 = vb.y * cb.y, p6 = vb.z * cb.z, p7 = vb.w * cb.w;
    float l0 = p0 + p4, l1 = p1 + p5, l2 = p2 + p6, l3 = p3 + p7;
    float vc = (l0 + l2) + (l1 + l3);
    float tt = vsq - 2.0f * vc;
    float u  = tt + csq[c];
    return -u;
}

// Exact numpy-order argmax incl. softmax tie path. Byte-identical semantics to
// the validated kernel (absmax == 0.0). Rare (delta-guard) path only.
__device__ __attribute__((noinline))
int exact_search(const float* __restrict__ cbf, const float* __restrict__ csq,
                 float4 va, float4 vb, float vsq)
{
#pragma clang fp contract(off)
    float best = -3.402823466e38f, second = -3.402823466e38f;
    int bi = 0;
    for (int c = 0; c < C; ++c) {
        float pr = proba_np(cbf, csq, c, va, vb, vsq);
        if (pr > best)        { second = best; best = pr; bi = c; }
        else if (pr > second) { second = pr; }
    }
    int idx = bi;

    if (best - second <= 1.0e-6f) {
        float m = best;
        float r0[8] = {0,0,0,0,0,0,0,0};
        float r1[8] = {0,0,0,0,0,0,0,0};
        for (int cg = 0; cg < 16; ++cg) {
            #pragma unroll
            for (int j = 0; j < 8; ++j) {
                float pr = proba_np(cbf, csq, cg * 8 + j, va, vb, vsq);
                r0[j] += expf(pr - m);
            }
        }
        for (int cg = 16; cg < 32; ++cg) {
            #pragma unroll
            for (int j = 0; j < 8; ++j) {
                float pr = proba_np(cbf, csq, cg * 8 + j, va, vb, vsq);
                r1[j] += expf(pr - m);
            }
        }
        float sum = tree8(r0[0],r0[1],r0[2],r0[3],r0[4],r0[5],r0[6],r0[7])
                  + tree8(r1[0],r1[1],r1[2],r1[3],r1[4],r1[5],r1[6],r1[7]);
        float abest = -1.0f;
        int   ai    = 0;
        for (int c = 0; c < C; ++c) {
            float pr = proba_np(cbf, csq, c, va, vb, vsq);
            float e  = expf(pr - m);
            float a  = e / sum;
            if (a > abest) { abest = a; ai = c; }
        }
        idx = ai;
    }
    return idx;
}

// ROUND 7: R0 structure + PACKED-FP32 hot loop (centroid-paired v_pk_fma_f32).
// Evidence synthesis R0-R6: duration is insensitive to operand source, register
// allocation and scheduling, but scales with issued ops/pair (R3: +35% ops ->
// +37% time). Working theory: VALU-issue-bound on an effectively diminished
// machine (harness memset runs at 0.1% of HBM peak => sliced/contended). Only
// remaining lever: fewer issued instructions.
//   - Centroids (c, c+1) are adjacent in LDS: operand pairs {cc[j], cc[j+8]}
//     come from ds_read2_b32; the 8-FMA chain becomes 8 v_pk_fma_f32 covering
//     BOTH centroids (va/vb scalars broadcast via op_sel). Per-half chain =
//     identical fmaf sequence -> s0,s1 bit-identical to the validated scan.
//   - Fused pair top-2/argmax update, proven == sequential c then c+1:
//     t=max(s0,best) is exactly the post-c0 best; second gets
//     max3(second, min(s0,best), min(s1,t)); first-wins priority preserved.
// Net: ~68 VALU + 9 LDS per 2 centroids vs 104 + 6 (-30% issue).
// Merge, 2e-5 guard, exact path, store: unchanged from R0 (12.3MB writes).
__global__ __launch_bounds__(TPB, 6)
void pq_split_kernel(const float* __restrict__ vecs,
                     const float* __restrict__ codebook,
                     float* __restrict__ out)
{
    __shared__ float  cbf [C * SD];          // 8 KB codebook[p]
    __shared__ float  csqn[C];               // ||c||^2 numpy order (exact path)
    __shared__ float  csqh[C];               // -0.5*csq (fast seed)
    __shared__ float2 part_bs[WPB][ROWS][64];  // 8 KB (best, second)
    __shared__ int    part_i [WPB][ROWS][64];  // 4 KB argmax per range

    const int p = blockIdx.x;
    const int t = threadIdx.x;
    const int w = t >> 6;          // wave id 0..3
    const int l = t & 63;          // lane id
    const int rowbase = blockIdx.y * (64 * ROWS);

    // ---- stage codebook[p]: 512 float4, 2 per thread ----
    const float4* src = (const float4*)(codebook + (size_t)p * C * SD);
    ((float4*)cbf)[t]       = src[t];
    ((float4*)cbf)[t + 256] = src[t + 256];
    __syncthreads();

    // ---- csq (numpy order) + fast seed, 1 centroid per thread ----
    {
        const float* cc = cbf + t * SD;
        float q0 = cc[0]*cc[0], q1 = cc[1]*cc[1], q2 = cc[2]*cc[2], q3 = cc[3]*cc[3];
        float q4 = cc[4]*cc[4], q5 = cc[5]*cc[5], q6 = cc[6]*cc[6], q7 = cc[7]*cc[7];
        float s = tree8(q0,q1,q2,q3,q4,q5,q6,q7);
        csqn[t] = s;
        csqh[t] = -0.5f * s;
    }
    __syncthreads();

    // ---- load this thread's ROWS sub-vectors ----
    float4 va[ROWS], vb[ROWS];
    #pragma unroll
    for (int r = 0; r < ROWS; ++r) {
        const float* vptr = vecs + (size_t)(rowbase + 64 * r + l) * D + (size_t)p * SD;
        va[r] = ((const float4*)vptr)[0];
        vb[r] = ((const float4*)vptr)[1];
    }

    // ---- fast scoring over this wave's 64 centroids, 2 per iteration ----
    float best[ROWS], second[ROWS];
    int   bi[ROWS];
    #pragma unroll
    for (int r = 0; r < ROWS; ++r) {
        best[r] = -3.402823466e38f; second[r] = -3.402823466e38f; bi[r] = 0;
    }

    const int c0 = w * CPW;
    #pragma unroll 2
    for (int ci = 0; ci < CPW; ci += 2) {
        const int c = c0 + ci;
        const float* cc = cbf + (size_t)c * SD;   // centroids c (cc[0..7]) and
                                                  // c+1 (cc[8..15]) adjacent
        f32x2 k0; k0.x = cc[0]; k0.y = cc[8];     // -> ds_read2_b32 pairs
        f32x2 k1; k1.x = cc[1]; k1.y = cc[9];
        f32x2 k2; k2.x = cc[2]; k2.y = cc[10];
        f32x2 k3; k3.x = cc[3]; k3.y = cc[11];
        f32x2 k4; k4.x = cc[4]; k4.y = cc[12];
        f32x2 k5; k5.x = cc[5]; k5.y = cc[13];
        f32x2 k6; k6.x = cc[6]; k6.y = cc[14];
        f32x2 k7; k7.x = cc[7]; k7.y = cc[15];
        f32x2 h2; h2.x = csqh[c]; h2.y = csqh[c + 1];

        #pragma unroll
        for (int r = 0; r < ROWS; ++r) {
            // both halves run the validated chain: seed ch, then x,y,z,w,x,y,z,w
            f32x2 s = pkfma(va[r].x, k0, h2);
            s = pkfma(va[r].y, k1, s);
            s = pkfma(va[r].z, k2, s);
            s = pkfma(va[r].w, k3, s);
            s = pkfma(vb[r].x, k4, s);
            s = pkfma(vb[r].y, k5, s);
            s = pkfma(vb[r].z, k6, s);
            s = pkfma(vb[r].w, k7, s);
            float s0 = s.x, s1 = s.y;

            // fused pair update == sequential (c, then c+1):
            //   t = max(s0, best) is exactly the post-c0 best.
            float tt  = fmaxf(s0, best[r]);
            bool  gt0 = s0 > best[r];
            bool  gt1 = s1 > tt;
            float m0  = fminf(s0, best[r]);
            float m1  = fminf(s1, tt);
            second[r] = fmaxf(second[r], fmaxf(m0, m1));   // v_max3_f32
            bi[r]     = gt1 ? (c + 1) : (gt0 ? c : bi[r]);
            best[r]   = fmaxf(tt, s1);
        }
    }

    // ---- publish partials ----
    #pragma unroll
    for (int r = 0; r < ROWS; ++r) {
        part_bs[w][r][l] = make_float2(best[r], second[r]);
        part_i [w][r][l] = bi[r];
    }
    __syncthreads();

    // ---- merge: thread t resolves row rowbase + t (its own j == w, lane l) ----
    {
        float Bst = -3.402823466e38f, Snd = -3.402823466e38f;
        int   I   = 0;
        #pragma unroll
        for (int ww = 0; ww < WPB; ++ww) {
            float2 bs = part_bs[ww][w][l];
            int    iw = part_i [ww][w][l];
            bool gt = bs.x > Bst;                 // strict, ascending ww:
            Snd = fmaxf(Snd, fminf(bs.x, Bst));   // first (smaller c) wins ties
            Snd = fmaxf(Snd, bs.y);
            I   = gt ? iw : I;
            Bst = fmaxf(Bst, bs.x);
        }

        const int row = rowbase + t;
        int idx = I;
        if (Bst - Snd <= 2.0e-5f) {               // near-tie: exact numpy path
            const float* vptr = vecs + (size_t)row * D + (size_t)p * SD;
            float4 xa = ((const float4*)vptr)[0];
            float4 xb = ((const float4*)vptr)[1];
            float q0 = xa.x*xa.x, q1 = xa.y*xa.y, q2 = xa.z*xa.z, q3 = xa.w*xa.w;
            float q4 = xb.x*xb.x, q5 = xb.y*xb.y, q6 = xb.z*xb.z, q7 = xb.w*xb.w;
            float vsq = tree8(q0,q1,q2,q3,q4,q5,q6,q7);
            idx = exact_search(cbf, csqn, xa, xb, vsq);
        }

        float4 o0 = ((const float4*)cbf)[2 * idx];
        float4 o1 = ((const float4*)cbf)[2 * idx + 1];
        float4* op = (float4*)(out + (size_t)row * D + (size_t)p * SD);
        op[0] = o0;
        op[1] = o1;
    }
}

extern "C" void kernel_launch(void* const* d_in, const int* in_sizes, int n_in,
                              void* d_out, int out_size, void* d_ws, size_t ws_size,
                              hipStream_t stream)
{
    const float* vecs     = (const float*)d_in[0];  // [B, D] fp32
    const float* codebook = (const float*)d_in[1];  // [P, C, SD] fp32
    float*       out      = (float*)d_out;          // [B, D] fp32

    dim3 grid(P, B / (64 * ROWS));   // (96, 16) -> 1536 blocks x 4 waves
    dim3 block(TPB);
    pq_split_kernel<<<grid, block, 0, stream>>>(vecs, codebook, out);
}

// Round 8
// 171.639 us; speedup vs baseline: 2.8818x; 2.8818x over previous
//
#include <hip/hip_runtime.h>
#include <cmath>

// Problem constants (fixed by the reference).
constexpr int B  = 4096;
constexpr int D  = 768;
constexpr int P  = 96;
constexpr int C  = 256;
constexpr int SD = 8;    // D / P

constexpr int TPB  = 256;   // 4 waves per block
constexpr int WPB  = 4;     // waves per block (centroid split)
constexpr int CPW  = C / WPB;  // 64 centroids per wave
constexpr int ROWS = 4;     // rows per thread

typedef float f32x2 __attribute__((ext_vector_type(2)));

// Packed fp32 FMA, scalar b broadcast to both halves (op_sel on gfx950's
// v_pk_fma_f32). Each half is IEEE fma == fmaf => per-row arithmetic is
// bit-identical to the validated scalar chain.
__device__ __forceinline__ f32x2 pkfma(f32x2 a, float b, f32x2 c)
{
    f32x2 bv; bv.x = b; bv.y = b;
    return __builtin_elementwise_fma(a, bv, c);
}

// ---- numpy fp32 emulation helpers (exact path only, validated absmax=0) ----
__device__ __forceinline__ float tree8(float q0, float q1, float q2, float q3,
                                       float q4, float q5, float q6, float q7)
{
#pragma clang fp contract(off)
    return ((q0 + q1) + (q2 + q3)) + ((q4 + q5) + (q6 + q7));
}

__device__ __forceinline__ float proba_np(const float* __restrict__ cbf,
                                          const float* __restrict__ csq,
                                          int c, float4 va, float4 vb, float vsq)
{
#pragma clang fp contract(off)
    float4 ca = ((const float4*)cbf)[2 * c];
    float4 cb = ((const float4*)cbf)[2 * c + 1];
    float p0 = va.x * ca.x, p1 = va.y * ca.y, p2 = va.z * ca.z, p3 = va.w * ca.w;
    float p4 = vb.x * cb.x, p5 = vb.y * cb.y, p6 = vb.z * cb.z, p7 = vb.w * cb.w;
    float l0 = p0 + p4, l1 = p1 + p5, l2 = p2 + p6, l3 = p3 + p7;
    float vc = (l0 + l2) + (l1 + l3);
    float tt = vsq - 2.0f * vc;
    float u  = tt + csq[c];
    return -u;
}

// Exact numpy-order argmax incl. softmax tie path. Byte-identical semantics to
// the validated kernel (absmax == 0.0). Rare (delta-guard) path only.
__device__ __attribute__((noinline))
int exact_search(const float* __restrict__ cbf, const float* __restrict__ csq,
                 float4 va, float4 vb, float vsq)
{
#pragma clang fp contract(off)
    float best = -3.402823466e38f, second = -3.402823466e38f;
    int bi = 0;
    for (int c = 0; c < C; ++c) {
        float pr = proba_np(cbf, csq, c, va, vb, vsq);
        if (pr > best)        { second = best; best = pr; bi = c; }
        else if (pr > second) { second = pr; }
    }
    int idx = bi;

    if (best - second <= 1.0e-6f) {
        float m = best;
        float r0[8] = {0,0,0,0,0,0,0,0};
        float r1[8] = {0,0,0,0,0,0,0,0};
        for (int cg = 0; cg < 16; ++cg) {
            #pragma unroll
            for (int j = 0; j < 8; ++j) {
                float pr = proba_np(cbf, csq, cg * 8 + j, va, vb, vsq);
                r0[j] += expf(pr - m);
            }
        }
        for (int cg = 16; cg < 32; ++cg) {
            #pragma unroll
            for (int j = 0; j < 8; ++j) {
                float pr = proba_np(cbf, csq, cg * 8 + j, va, vb, vsq);
                r1[j] += expf(pr - m);
            }
        }
        float sum = tree8(r0[0],r0[1],r0[2],r0[3],r0[4],r0[5],r0[6],r0[7])
                  + tree8(r1[0],r1[1],r1[2],r1[3],r1[4],r1[5],r1[6],r1[7]);
        float abest = -1.0f;
        int   ai    = 0;
        for (int c = 0; c < C; ++c) {
            float pr = proba_np(cbf, csq, c, va, vb, vsq);
            float e  = expf(pr - m);
            float a  = e / sum;
            if (a > abest) { abest = a; ai = c; }
        }
        idx = ai;
    }
    return idx;
}

// ROUND 8: R0 skeleton + ROW-PACKED v_pk_fma_f32 hot loop (spill-proof).
// Model from R0-R7: dur ~= ceil(blocks/256) x L, L proportional to issued
// wave-instructions (R3: +155% inst -> +174% per-block time; R7's scratch
// +450us). Only working lever: fewer issued instructions. R7's centroid-paired
// pk_fma died to per-iteration pair construction through scratch (FETCH 25MB
// -> 1.25GB). Fix: pack across ROWS -- {va[0].x, va[1].x} etc. are LOOP-
// INVARIANT f32x2 (16 named registers, packed once); the shared per-centroid
// scalars (ca.*, ch) broadcast via op_sel. 16 pk_fma replace 32 fma per
// centroid. Tracker: fmaxf(second, fminf(s,best)) == fmed3(s,best,second)
// given second<=best invariant (median of {s,b,2nd} is the new second) ->
// explicit v_med3_f32, 4 ops/row. Per-iter issue ~55 -> ~38 (-30%).
// Each pk half is IEEE fma running the identical validated sequence; tracker
// updates per-row strictly c-sequential => bit-identical (best,second,idx).
// Merge, 2e-5 guard, exact path, store: R0 verbatim. NO arrays in hot scope
// (all named scalars) to deny the allocator any scratch temptation.
__global__ __launch_bounds__(TPB, 6)
void pq_split_kernel(const float* __restrict__ vecs,
                     const float* __restrict__ codebook,
                     float* __restrict__ out)
{
    __shared__ float  cbf [C * SD];          // 8 KB codebook[p]
    __shared__ float  csqn[C];               // ||c||^2 numpy order (exact path)
    __shared__ float  csqh[C];               // -0.5*csq (fast seed)
    __shared__ float2 part_bs[WPB][ROWS][64];  // 8 KB (best, second)
    __shared__ int    part_i [WPB][ROWS][64];  // 4 KB argmax per range

    const int p = blockIdx.x;
    const int t = threadIdx.x;
    const int w = t >> 6;          // wave id 0..3
    const int l = t & 63;          // lane id
    const int rowbase = blockIdx.y * (64 * ROWS);

    // ---- stage codebook[p]: 512 float4, 2 per thread ----
    const float4* src = (const float4*)(codebook + (size_t)p * C * SD);
    ((float4*)cbf)[t]       = src[t];
    ((float4*)cbf)[t + 256] = src[t + 256];
    __syncthreads();

    // ---- csq (numpy order) + fast seed, 1 centroid per thread ----
    {
        const float* cc = cbf + t * SD;
        float q0 = cc[0]*cc[0], q1 = cc[1]*cc[1], q2 = cc[2]*cc[2], q3 = cc[3]*cc[3];
        float q4 = cc[4]*cc[4], q5 = cc[5]*cc[5], q6 = cc[6]*cc[6], q7 = cc[7]*cc[7];
        float s = tree8(q0,q1,q2,q3,q4,q5,q6,q7);
        csqn[t] = s;
        csqh[t] = -0.5f * s;
    }
    __syncthreads();

    // ---- load this thread's 4 sub-vectors (named, no arrays) ----
    const float* vp0 = vecs + (size_t)(rowbase +   0 + l) * D + (size_t)p * SD;
    const float* vp1 = vecs + (size_t)(rowbase +  64 + l) * D + (size_t)p * SD;
    const float* vp2 = vecs + (size_t)(rowbase + 128 + l) * D + (size_t)p * SD;
    const float* vp3 = vecs + (size_t)(rowbase + 192 + l) * D + (size_t)p * SD;
    float4 va0 = ((const float4*)vp0)[0], vb0 = ((const float4*)vp0)[1];
    float4 va1 = ((const float4*)vp1)[0], vb1 = ((const float4*)vp1)[1];
    float4 va2 = ((const float4*)vp2)[0], vb2 = ((const float4*)vp2)[1];
    float4 va3 = ((const float4*)vp3)[0], vb3 = ((const float4*)vp3)[1];

    // ---- loop-invariant row-pair packs (16 named f32x2, packed ONCE) ----
    f32x2 ax01; ax01.x = va0.x; ax01.y = va1.x;
    f32x2 ay01; ay01.x = va0.y; ay01.y = va1.y;
    f32x2 az01; az01.x = va0.z; az01.y = va1.z;
    f32x2 aw01; aw01.x = va0.w; aw01.y = va1.w;
    f32x2 bx01; bx01.x = vb0.x; bx01.y = vb1.x;
    f32x2 by01; by01.x = vb0.y; by01.y = vb1.y;
    f32x2 bz01; bz01.x = vb0.z; bz01.y = vb1.z;
    f32x2 bw01; bw01.x = vb0.w; bw01.y = vb1.w;
    f32x2 ax23; ax23.x = va2.x; ax23.y = va3.x;
    f32x2 ay23; ay23.x = va2.y; ay23.y = va3.y;
    f32x2 az23; az23.x = va2.z; az23.y = va3.z;
    f32x2 aw23; aw23.x = va2.w; aw23.y = va3.w;
    f32x2 bx23; bx23.x = vb2.x; bx23.y = vb3.x;
    f32x2 by23; by23.x = vb2.y; by23.y = vb3.y;
    f32x2 bz23; bz23.x = vb2.z; bz23.y = vb3.z;
    f32x2 bw23; bw23.x = vb2.w; bw23.y = vb3.w;

    // ---- fast scoring over this wave's 64 centroids (branchless top-2) ----
    float best0 = -3.402823466e38f, best1 = -3.402823466e38f;
    float best2 = -3.402823466e38f, best3 = -3.402823466e38f;
    float sec0  = -3.402823466e38f, sec1  = -3.402823466e38f;
    float sec2  = -3.402823466e38f, sec3  = -3.402823466e38f;
    int   bi0 = 0, bi1 = 0, bi2 = 0, bi3 = 0;

    const int c0 = w * CPW;
    #pragma unroll 2
    for (int ci = 0; ci < CPW; ++ci) {
        const int c = c0 + ci;
        float4 ca = ((const float4*)cbf)[2 * c];     // wave-uniform broadcast
        float4 cb = ((const float4*)cbf)[2 * c + 1];
        float  ch = csqh[c];
        f32x2 chv; chv.x = ch; chv.y = ch;

        // rows 0,1 and 2,3: identical validated chain per half
        f32x2 s01 = pkfma(ax01, ca.x, chv);
        s01 = pkfma(ay01, ca.y, s01);
        s01 = pkfma(az01, ca.z, s01);
        s01 = pkfma(aw01, ca.w, s01);
        s01 = pkfma(bx01, cb.x, s01);
        s01 = pkfma(by01, cb.y, s01);
        s01 = pkfma(bz01, cb.z, s01);
        s01 = pkfma(bw01, cb.w, s01);
        f32x2 s23 = pkfma(ax23, ca.x, chv);
        s23 = pkfma(ay23, ca.y, s23);
        s23 = pkfma(az23, ca.z, s23);
        s23 = pkfma(aw23, ca.w, s23);
        s23 = pkfma(bx23, cb.x, s23);
        s23 = pkfma(by23, cb.y, s23);
        s23 = pkfma(bz23, cb.z, s23);
        s23 = pkfma(bw23, cb.w, s23);

        // per-row trackers, strictly c-sequential; med3 == max(sec,min(s,best))
        // under the invariant sec <= best (median of {s,best,sec} = new sec).
        {
            float s = s01.x;
            bool gt = s > best0;
            sec0  = __builtin_amdgcn_fmed3f(s, best0, sec0);
            bi0   = gt ? c : bi0;
            best0 = fmaxf(s, best0);
        }
        {
            float s = s01.y;
            bool gt = s > best1;
            sec1  = __builtin_amdgcn_fmed3f(s, best1, sec1);
            bi1   = gt ? c : bi1;
            best1 = fmaxf(s, best1);
        }
        {
            float s = s23.x;
            bool gt = s > best2;
            sec2  = __builtin_amdgcn_fmed3f(s, best2, sec2);
            bi2   = gt ? c : bi2;
            best2 = fmaxf(s, best2);
        }
        {
            float s = s23.y;
            bool gt = s > best3;
            sec3  = __builtin_amdgcn_fmed3f(s, best3, sec3);
            bi3   = gt ? c : bi3;
            best3 = fmaxf(s, best3);
        }
    }

    // ---- publish partials ----
    part_bs[w][0][l] = make_float2(best0, sec0);  part_i[w][0][l] = bi0;
    part_bs[w][1][l] = make_float2(best1, sec1);  part_i[w][1][l] = bi1;
    part_bs[w][2][l] = make_float2(best2, sec2);  part_i[w][2][l] = bi2;
    part_bs[w][3][l] = make_float2(best3, sec3);  part_i[w][3][l] = bi3;
    __syncthreads();

    // ---- merge: thread t resolves row rowbase + t (its own j == w, lane l) ----
    {
        float Bst = -3.402823466e38f, Snd = -3.402823466e38f;
        int   I   = 0;
        #pragma unroll
        for (int ww = 0; ww < WPB; ++ww) {
            float2 bs = part_bs[ww][w][l];
            int    iw = part_i [ww][w][l];
            bool gt = bs.x > Bst;                 // strict, ascending ww:
            Snd = fmaxf(Snd, fminf(bs.x, Bst));   // first (smaller c) wins ties
            Snd = fmaxf(Snd, bs.y);
            I   = gt ? iw : I;
            Bst = fmaxf(Bst, bs.x);
        }

        const int row = rowbase + t;
        int idx = I;
        if (Bst - Snd <= 2.0e-5f) {               // near-tie: exact numpy path
            const float* vptr = vecs + (size_t)row * D + (size_t)p * SD;
            float4 xa = ((const float4*)vptr)[0];
            float4 xb = ((const float4*)vptr)[1];
            float q0 = xa.x*xa.x, q1 = xa.y*xa.y, q2 = xa.z*xa.z, q3 = xa.w*xa.w;
            float q4 = xb.x*xb.x, q5 = xb.y*xb.y, q6 = xb.z*xb.z, q7 = xb.w*xb.w;
            float vsq = tree8(q0,q1,q2,q3,q4,q5,q6,q7);
            idx = exact_search(cbf, csqn, xa, xb, vsq);
        }

        float4 o0 = ((const float4*)cbf)[2 * idx];
        float4 o1 = ((const float4*)cbf)[2 * idx + 1];
        float4* op = (float4*)(out + (size_t)row * D + (size_t)p * SD);
        op[0] = o0;
        op[1] = o1;
    }
}

extern "C" void kernel_launch(void* const* d_in, const int* in_sizes, int n_in,
                              void* d_out, int out_size, void* d_ws, size_t ws_size,
                              hipStream_t stream)
{
    const float* vecs     = (const float*)d_in[0];  // [B, D] fp32
    const float* codebook = (const float*)d_in[1];  // [P, C, SD] fp32
    float*       out      = (float*)d_out;          // [B, D] fp32

    dim3 grid(P, B / (64 * ROWS));   // (96, 16) -> 1536 blocks x 4 waves
    dim3 block(TPB);
    pq_split_kernel<<<grid, block, 0, stream>>>(vecs, codebook, out);
}